// Round 11
// baseline (253.814 us; speedup 1.0000x reference)
//
#include <hip/hip_runtime.h>

#define NN 50000
#define NE 800000
#define DEGCAP 64                              // max in-degree (Poisson(16): P(>64)~1e-15)

// K1 geometry: scatter blocks FIRST (XCD classes + overlap with cvt)
#define NXCD 8
#define NPS ((NN + NXCD - 1) / NXCD)           // 6250 nodes per XCD slot
#define SEPB 4096                              // edges per chunk
#define NCHUNK ((NE + SEPB - 1) / SEPB)        // 196
#define SCAT_BLKS (NCHUNK * NXCD)              // 1568
#define CVT_BLKS 6250                          // NN*128/4/256 exactly
#define PREP_BLKS 32
#define K1_GRID (SCAT_BLKS + CVT_BLKS + PREP_BLKS + 1)

typedef short short8 __attribute__((ext_vector_type(8)));
typedef short short4v __attribute__((ext_vector_type(4)));
typedef float f32x4 __attribute__((ext_vector_type(4)));
typedef _Float16 half8v __attribute__((ext_vector_type(8)));

__device__ inline unsigned short f16_bits(float f) {
    _Float16 h = (_Float16)f;                  // v_cvt_f16_f32, RNE
    return __builtin_bit_cast(unsigned short, h);
}

// ---- K1: scatter (XCD-partitioned, u16) | cvt x->fp16 | wprep | zero-rows --
// r10-validated verbatim. deg=0 via hipMemsetAsync before this launch.
__global__ __launch_bounds__(256) void k1_kernel(const float* __restrict__ x,
                                                 unsigned short* __restrict__ xb,
                                                 const float* __restrict__ W0,
                                                 const float* __restrict__ W1,
                                                 const float* __restrict__ W2,
                                                 const float* __restrict__ W3,
                                                 short* __restrict__ wf,
                                                 int* __restrict__ deg,
                                                 unsigned short* __restrict__ col,
                                                 const int* __restrict__ src,
                                                 const int* __restrict__ dst,
                                                 unsigned short* __restrict__ h1b) {
    int b = blockIdx.x;
    if (b < SCAT_BLKS) {                      // edge scatter (r8-validated)
        int slot8 = b & 7;                    // stable XCD class (round-robin dispatch)
        int chunk = b >> 3;
        int lo = slot8 * NPS, hi = lo + NPS;
        int base = chunk * SEPB;
        int end = base + SEPB;
        if (end > NE) end = NE;
        for (int i = base + (int)threadIdx.x; i < end; i += 256) {
            int d = dst[i];
            if (d >= lo && d < hi) {
                int s = src[i];
                int sl = atomicAdd(&deg[d], 1);
                col[((size_t)d << 6) + sl] = (unsigned short)s;
            }
        }
    } else if (b < SCAT_BLKS + CVT_BLKS) {    // x -> fp16 (one float4/thread, exact)
        int i = (b - SCAT_BLKS) * 256 + threadIdx.x;
        float4 v = ((const float4*)x)[i];
        short4v r;
        r[0] = (short)f16_bits(v.x);
        r[1] = (short)f16_bits(v.y);
        r[2] = (short)f16_bits(v.z);
        r[3] = (short)f16_bits(v.w);
        ((short4v*)xb)[i] = r;
    } else if (b < SCAT_BLKS + CVT_BLKS + PREP_BLKS) {  // weight fragment reorder
        int t = (b - SCAT_BLKS - CVT_BLKS) * 256 + threadIdx.x;   // 0..8191
        int mat = t >> 11;
        const float* W = (mat == 0) ? W0 : (mat == 1) ? W1 : (mat == 2) ? W2 : W3;
        short* out = wf + (size_t)mat * 16384;
        int r = t & 2047;
        int nt = r >> 8;
        int kc = (r >> 6) & 3;
        int lane = r & 63;
        int n = nt * 16 + (lane & 15);
        int kbase = kc * 32 + ((lane >> 4) << 3);
        short8 vh;
#pragma unroll
        for (int j = 0; j < 8; ++j) {
            float w = W[(size_t)(kbase + j) * 128 + n];
            vh[j] = (short)f16_bits(w);
        }
        size_t o = ((size_t)((nt * 4 + kc) * 64 + lane)) * 8;
        *(short8*)(out + o) = vh;
    } else {                                  // zero feature rows at index NN
        int t = threadIdx.x;
        short8 z = {0, 0, 0, 0, 0, 0, 0, 0};
        if (t < 16) *(short8*)(xb + ((size_t)NN << 7) + (t << 3)) = z;
        else if (t < 32) *(short8*)(h1b + ((size_t)NN << 7) + ((t - 16) << 3)) = z;
    }
}

// ---- fused SAGE layer via LDS: r8 agg loop -> syncthreads -> MFMA ----------
// Block = 64 rows, 4 waves. Phase 1: wave w aggregates nodes w*16..w*16+15
// with the r8-WINNING loop (one node per wave-step, 4 slots x 16 sub lanes,
// coalesced 256B row reads, zero divergence, 16 edges in flight). fp16 mean
// goes to a padded LDS tile (stride 136 halves = 68 dwords -> 4-bank row
// shift, max 2-way aliasing = free). Phase 2: wave w MFMAs rows w*16..+15,
// A0 from LDS, A1 (root) from global. Removes aggb round-trip + 2 launches
// while keeping r8 gather speed (r10's fragment-layout gather was 9us/layer
// slower from degree divergence).
__global__ __launch_bounds__(256) void sage_layer(const unsigned short* __restrict__ hb,
                                                  const unsigned short* __restrict__ col,
                                                  const int* __restrict__ deg,
                                                  const short* __restrict__ Wf0,
                                                  const short* __restrict__ Wf1,
                                                  const float* __restrict__ bias,
                                                  unsigned short* __restrict__ outb,
                                                  const float* __restrict__ Wfc,
                                                  const float* __restrict__ bfc,
                                                  float* __restrict__ fcout,
                                                  int relu) {
    __shared__ unsigned short agg_s[64][136];      // 17.4 KB, +8 pad per row
    int lane = threadIdx.x & 63;
    int wv = threadIdx.x >> 6;
    int slot = lane >> 4, sub = lane & 15;
    int row_base = blockIdx.x * 64;

    // ---- phase 1: aggregate 16 nodes per wave (r8 structure) ----
    const unsigned short* gbase = hb + (sub << 3);
    for (int i = 0; i < 16; ++i) {
        int li = wv * 16 + i;
        int node = row_base + li;
        if (node >= NN) {                          // wave-uniform branch
            if (slot == 0) {
                short8 z = {0, 0, 0, 0, 0, 0, 0, 0};
                *(short8*)&agg_s[li][sub << 3] = z;
            }
            continue;
        }
        int dg = deg[node];
        const unsigned short* cp = col + ((size_t)node << 6);
        float acc[8];
#pragma unroll
        for (int j = 0; j < 8; ++j) acc[j] = 0.f;
        for (int e0 = slot; e0 < dg; e0 += 16) {   // 16 edges in flight per wave
            int c[4];
#pragma unroll
            for (int j = 0; j < 4; ++j) {
                int e = e0 + 4 * j;
                int cc = cp[e < DEGCAP ? e : 0];   // in-bounds read (value may be junk)
                c[j] = (e < dg) ? cc : NN;         // junk/overflow lanes -> zero row
            }
            half8v v[4];
#pragma unroll
            for (int j = 0; j < 4; ++j) v[j] = *(const half8v*)(gbase + ((size_t)c[j] << 7));
            half8v s = (v[0] + v[1]) + (v[2] + v[3]);   // fp16 tree (r5/r6-validated)
#pragma unroll
            for (int q = 0; q < 8; ++q) acc[q] += (float)s[q];
        }
#pragma unroll
        for (int j = 0; j < 8; ++j) {
            acc[j] += __shfl_xor(acc[j], 16, 64);
            acc[j] += __shfl_xor(acc[j], 32, 64);
        }
        if (slot == 0) {
            float s = 1.0f / (float)(dg > 0 ? dg : 1);
            short8 o;
#pragma unroll
            for (int j = 0; j < 8; ++j) o[j] = (short)f16_bits(acc[j] * s);
            *(short8*)&agg_s[li][sub << 3] = o;
        }
    }
    __syncthreads();

    // ---- phase 2: MFMA for this wave's 16-row tile ----
    int quad = slot, m16 = sub;                    // same decomposition
    int tb = row_base + wv * 16;                   // tile row base
    int arow = tb + m16;
    if (arow > NN - 1) arow = NN - 1;              // clamp (padding rows never stored)

    half8v a0[4], a1[4];
#pragma unroll
    for (int kc = 0; kc < 4; ++kc) {
        a0[kc] = *(const half8v*)&agg_s[wv * 16 + m16][kc * 32 + (quad << 3)];
        a1[kc] = *(const half8v*)(hb + ((size_t)arow << 7) + kc * 32 + (quad << 3));
    }

    f32x4 acc[8];
#pragma unroll
    for (int nt = 0; nt < 8; ++nt) acc[nt] = (f32x4){0.f, 0.f, 0.f, 0.f};

#pragma unroll
    for (int kc = 0; kc < 4; ++kc) {
        const short* wp0 = Wf0 + ((size_t)kc * 64 + lane) * 8;
        const short* wp1 = Wf1 + ((size_t)kc * 64 + lane) * 8;
#pragma unroll
        for (int nt = 0; nt < 8; ++nt) {
            half8v b0 = *(const half8v*)(wp0 + (size_t)nt * 2048);
            half8v b1 = *(const half8v*)(wp1 + (size_t)nt * 2048);
            acc[nt] = __builtin_amdgcn_mfma_f32_16x16x32_f16(a0[kc], b0, acc[nt], 0, 0, 0);
            acc[nt] = __builtin_amdgcn_mfma_f32_16x16x32_f16(a1[kc], b1, acc[nt], 0, 0, 0);
        }
    }

    // epilogue: C/D layout col = lane&15, row = quad*4 + reg
    float bcol[8];
#pragma unroll
    for (int nt = 0; nt < 8; ++nt) bcol[nt] = bias[nt * 16 + m16];

    if (Wfc) {
        // fused final FC: lane holds cols nt*16+m16; reduce over 16 m16-lanes
        float w0[8], w1[8];
#pragma unroll
        for (int nt = 0; nt < 8; ++nt) {
            float2 wv2 = *(const float2*)(Wfc + 2 * (nt * 16 + m16));
            w0[nt] = wv2.x;
            w1[nt] = wv2.y;
        }
        float b0 = bfc[0], b1 = bfc[1];
#pragma unroll
        for (int r = 0; r < 4; ++r) {
            float p0 = 0.f, p1 = 0.f;
#pragma unroll
            for (int nt = 0; nt < 8; ++nt) {
                float v = fmaxf(acc[nt][r] + bcol[nt], 0.f);   // relu (layer2)
                p0 += v * w0[nt];
                p1 += v * w1[nt];
            }
#pragma unroll
            for (int off = 1; off < 16; off <<= 1) {
                p0 += __shfl_xor(p0, off, 64);
                p1 += __shfl_xor(p1, off, 64);
            }
            int row = tb + quad * 4 + r;
            if (m16 == 0 && row < NN) {
                float2 o;
                o.x = p0 + b0;
                o.y = p1 + b1;
                *(float2*)(fcout + 2 * (size_t)row) = o;
            }
        }
    } else {
#pragma unroll
        for (int r = 0; r < 4; ++r) {
            int row = tb + quad * 4 + r;
            if (row >= NN) continue;
            unsigned short* opb = outb + ((size_t)row << 7) + m16;
#pragma unroll
            for (int nt = 0; nt < 8; ++nt) {
                float v = acc[nt][r] + bcol[nt];
                if (relu) v = fmaxf(v, 0.f);
                opb[nt * 16] = f16_bits(v);
            }
        }
    }
}

extern "C" void kernel_launch(void* const* d_in, const int* in_sizes, int n_in,
                              void* d_out, int out_size, void* d_ws, size_t ws_size,
                              hipStream_t stream) {
    const float* x   = (const float*)d_in[0];
    const int* edge  = (const int*)d_in[1];
    const float* W1l = (const float*)d_in[2];
    const float* W1r = (const float*)d_in[3];
    const float* b1  = (const float*)d_in[4];
    const float* W2l = (const float*)d_in[5];
    const float* W2r = (const float*)d_in[6];
    const float* b2  = (const float*)d_in[7];
    const float* Wfc = (const float*)d_in[8];
    const float* bfc = (const float*)d_in[9];
    float* out = (float*)d_out;

    const int* src = edge;        // edge_index[0]
    const int* dst = edge + NE;   // edge_index[1]

    char* ws = (char*)d_ws;
    size_t off = 0;
    auto alloc = [&](size_t bytes) -> char* {
        char* p = ws + off;
        off = (off + bytes + 511) & ~(size_t)511;
        return p;
    };
    int* deg              = (int*)alloc((size_t)NN * 4);
    short* wf             = (short*)alloc((size_t)4 * 16384 * 2);
    unsigned short* col   = (unsigned short*)alloc((size_t)NN * DEGCAP * 2);
    unsigned short* xb    = (unsigned short*)alloc((size_t)(NN + 1) * 128 * 2);
    unsigned short* h1b   = (unsigned short*)alloc((size_t)(NN + 1) * 128 * 2);
    (void)ws_size; (void)in_sizes; (void)n_in; (void)out_size;

    hipMemsetAsync(deg, 0, (size_t)NN * 4, stream);
    k1_kernel<<<K1_GRID, 256, 0, stream>>>(x, xb, W1l, W1r, W2l, W2r, wf,
                                           deg, col, src, dst, h1b);
    sage_layer<<<(NN + 63) / 64, 256, 0, stream>>>(xb, col, deg,
                                                   wf, wf + 16384, b1, h1b,
                                                   (const float*)0, (const float*)0,
                                                   (float*)0, 1);
    sage_layer<<<(NN + 63) / 64, 256, 0, stream>>>(h1b, col, deg,
                                                   wf + 2 * 16384, wf + 3 * 16384, b2,
                                                   (unsigned short*)0, Wfc, bfc, out, 0);
}

// Round 12
// 240.055 us; speedup vs baseline: 1.0573x; 1.0573x over previous
//
#include <hip/hip_runtime.h>

#define NN 50000
#define NE 800000
#define NCHK 4                                 // src chunks (12500 rows = 3.2MB, L2-fit)
#define CROWS 12500                            // rows per src chunk
#define CCAP 24                                // slots per (node,chunk); Poisson(4), P(>24)~1e-12
#define CSTRIDE (NCHK * CCAP)                  // 96 u16 per node

// K1 geometry: scatter blocks FIRST (XCD classes + overlap with cvt)
#define NXCD 8
#define NPS ((NN + NXCD - 1) / NXCD)           // 6250 nodes per XCD slot
#define SEPB 4096                              // edges per chunk
#define NCHUNK ((NE + SEPB - 1) / SEPB)        // 196
#define SCAT_BLKS (NCHUNK * NXCD)              // 1568
#define CVT_BLKS 6250                          // NN*128/4/256 exactly
#define PREP_BLKS 32
#define K1_GRID (SCAT_BLKS + CVT_BLKS + PREP_BLKS + 1)

typedef short short8 __attribute__((ext_vector_type(8)));
typedef short short4v __attribute__((ext_vector_type(4)));
typedef float f32x4 __attribute__((ext_vector_type(4)));
typedef _Float16 half8v __attribute__((ext_vector_type(8)));

__device__ inline unsigned short f16_bits(float f) {
    _Float16 h = (_Float16)f;                  // v_cvt_f16_f32, RNE
    return __builtin_bit_cast(unsigned short, h);
}

// ---- K1: scatter (XCD-part., src-chunk-binned u16) | cvt | wprep | zrows ---
// deg4[node*4+c] counts edges per src-chunk; col[node*96 + c*24 + slot].
__global__ __launch_bounds__(256) void k1_kernel(const float* __restrict__ x,
                                                 unsigned short* __restrict__ xb,
                                                 const float* __restrict__ W0,
                                                 const float* __restrict__ W1,
                                                 const float* __restrict__ W2,
                                                 const float* __restrict__ W3,
                                                 short* __restrict__ wf,
                                                 int* __restrict__ deg4,
                                                 unsigned short* __restrict__ col,
                                                 const int* __restrict__ src,
                                                 const int* __restrict__ dst,
                                                 unsigned short* __restrict__ h1b) {
    int b = blockIdx.x;
    if (b < SCAT_BLKS) {                      // edge scatter (r8-validated + chunk bin)
        int slot8 = b & 7;                    // stable XCD class (round-robin dispatch)
        int chunk = b >> 3;
        int lo = slot8 * NPS, hi = lo + NPS;
        int base = chunk * SEPB;
        int end = base + SEPB;
        if (end > NE) end = NE;
        for (int i = base + (int)threadIdx.x; i < end; i += 256) {
            int d = dst[i];
            if (d >= lo && d < hi) {
                int s = src[i];
                int c = s / CROWS;            // 0..3 (compiler magic-mul)
                int sl = atomicAdd(&deg4[d * NCHK + c], 1);
                col[(size_t)d * CSTRIDE + c * CCAP + sl] = (unsigned short)s;
            }
        }
    } else if (b < SCAT_BLKS + CVT_BLKS) {    // x -> fp16 (one float4/thread, exact)
        int i = (b - SCAT_BLKS) * 256 + threadIdx.x;
        float4 v = ((const float4*)x)[i];
        short4v r;
        r[0] = (short)f16_bits(v.x);
        r[1] = (short)f16_bits(v.y);
        r[2] = (short)f16_bits(v.z);
        r[3] = (short)f16_bits(v.w);
        ((short4v*)xb)[i] = r;
    } else if (b < SCAT_BLKS + CVT_BLKS + PREP_BLKS) {  // weight fragment reorder
        int t = (b - SCAT_BLKS - CVT_BLKS) * 256 + threadIdx.x;   // 0..8191
        int mat = t >> 11;
        const float* W = (mat == 0) ? W0 : (mat == 1) ? W1 : (mat == 2) ? W2 : W3;
        short* out = wf + (size_t)mat * 16384;
        int r = t & 2047;
        int nt = r >> 8;
        int kc = (r >> 6) & 3;
        int lane = r & 63;
        int n = nt * 16 + (lane & 15);
        int kbase = kc * 32 + ((lane >> 4) << 3);
        short8 vh;
#pragma unroll
        for (int j = 0; j < 8; ++j) {
            float w = W[(size_t)(kbase + j) * 128 + n];
            vh[j] = (short)f16_bits(w);
        }
        size_t o = ((size_t)((nt * 4 + kc) * 64 + lane)) * 8;
        *(short8*)(out + o) = vh;
    } else {                                  // zero feature rows at index NN
        int t = threadIdx.x;
        short8 z = {0, 0, 0, 0, 0, 0, 0, 0};
        if (t < 16) *(short8*)(xb + ((size_t)NN << 7) + (t << 3)) = z;
        else if (t < 32) *(short8*)(h1b + ((size_t)NN << 7) + ((t - 16) << 3)) = z;
    }
}

// ------- mean aggregation, src-chunk-phased: fp16 in, fp32 acc, fp16 out -----
// r8's winning structure (one wave per node, 50k waves, coalesced 256B rows,
// 16 loads in flight) + r11's diagnosis (FETCH 80MB/layer = 69% L2 miss on a
// 12.8MB table): walk the 4 src-chunks SEQUENTIALLY so all concurrent waves
// touch the same 3.2MB sub-table -> L2-resident per XCD, misses only on the
// first sweep (4x8x3.2MB = 102MB L3 vs 141MB before).
__global__ __launch_bounds__(256) void agg_kernel(const unsigned short* __restrict__ hb,
                                                  const unsigned short* __restrict__ col,
                                                  const int* __restrict__ deg4,
                                                  unsigned short* __restrict__ outb, int n) {
    int node = blockIdx.x * 4 + (threadIdx.x >> 6);
    if (node >= n) return;
    int lane = threadIdx.x & 63;
    int slot = lane >> 4, sub = lane & 15;
    const unsigned short* base = hb + (sub << 3);
    float acc[8];
#pragma unroll
    for (int j = 0; j < 8; ++j) acc[j] = 0.f;

    int dtot = 0;
#pragma unroll
    for (int c = 0; c < NCHK; ++c) {
        int dgc = deg4[node * NCHK + c];
        dtot += dgc;
        const unsigned short* cp = col + (size_t)node * CSTRIDE + c * CCAP;
        for (int e0 = slot; e0 < dgc; e0 += 16) {
            int ci[4];
#pragma unroll
            for (int j = 0; j < 4; ++j) {
                int e = e0 + 4 * j;
                int cc = cp[e < CCAP ? e : 0];         // in-bounds read (value may be junk)
                ci[j] = (e < dgc) ? cc : NN;           // junk/overflow lanes -> zero row
            }
            half8v v[4];
#pragma unroll
            for (int j = 0; j < 4; ++j) v[j] = *(const half8v*)(base + ((size_t)ci[j] << 7));
            half8v s = (v[0] + v[1]) + (v[2] + v[3]);  // fp16 tree (r5/r6-validated)
#pragma unroll
            for (int q = 0; q < 8; ++q) acc[q] += (float)s[q];
        }
    }
#pragma unroll
    for (int j = 0; j < 8; ++j) {
        acc[j] += __shfl_xor(acc[j], 16, 64);
        acc[j] += __shfl_xor(acc[j], 32, 64);
    }
    if (slot == 0) {
        float s = 1.0f / (float)(dtot > 0 ? dtot : 1);
        short8 o;
#pragma unroll
        for (int j = 0; j < 8; ++j) o[j] = (short)f16_bits(acc[j] * s);
        *(short8*)(outb + ((size_t)node << 7) + (sub << 3)) = o;
    }
}

// ---------------- fused dual GEMM, fp16 MFMA (+opt. fused FC) ----------------
__global__ __launch_bounds__(256) void gemm_mfma(const unsigned short* __restrict__ A0b,
                                                 const unsigned short* __restrict__ A1b,
                                                 const short* __restrict__ Wf0,
                                                 const short* __restrict__ Wf1,
                                                 const float* __restrict__ bias,
                                                 unsigned short* __restrict__ outb,
                                                 const float* __restrict__ Wfc,
                                                 const float* __restrict__ bfc,
                                                 float* __restrict__ fcout,
                                                 int n, int relu) {
    int lane = threadIdx.x & 63;
    int wave = threadIdx.x >> 6;
    int quad = lane >> 4, m16 = lane & 15;
    int row_base = blockIdx.x * 64 + wave * 16;
    int arow = row_base + m16;
    if (arow > n - 1) arow = n - 1;            // clamp (padding rows never stored)

    const unsigned short* ap0 = A0b + ((size_t)arow << 7) + (quad << 3);
    const unsigned short* ap1 = A1b + ((size_t)arow << 7) + (quad << 3);
    half8v a0[4], a1[4];
#pragma unroll
    for (int kc = 0; kc < 4; ++kc) {
        a0[kc] = *(const half8v*)(ap0 + kc * 32);
        a1[kc] = *(const half8v*)(ap1 + kc * 32);
    }

    f32x4 acc[8];
#pragma unroll
    for (int nt = 0; nt < 8; ++nt) acc[nt] = (f32x4){0.f, 0.f, 0.f, 0.f};

#pragma unroll
    for (int kc = 0; kc < 4; ++kc) {
        const short* wp0 = Wf0 + ((size_t)kc * 64 + lane) * 8;
        const short* wp1 = Wf1 + ((size_t)kc * 64 + lane) * 8;
#pragma unroll
        for (int nt = 0; nt < 8; ++nt) {
            half8v b0 = *(const half8v*)(wp0 + (size_t)nt * 2048);
            half8v b1 = *(const half8v*)(wp1 + (size_t)nt * 2048);
            acc[nt] = __builtin_amdgcn_mfma_f32_16x16x32_f16(a0[kc], b0, acc[nt], 0, 0, 0);
            acc[nt] = __builtin_amdgcn_mfma_f32_16x16x32_f16(a1[kc], b1, acc[nt], 0, 0, 0);
        }
    }

    // epilogue: C/D layout col = lane&15, row = quad*4 + reg
    float bcol[8];
#pragma unroll
    for (int nt = 0; nt < 8; ++nt) bcol[nt] = bias[nt * 16 + m16];

    if (Wfc) {
        // fused final FC: lane holds cols nt*16+m16; reduce over 16 m16-lanes
        float w0[8], w1[8];
#pragma unroll
        for (int nt = 0; nt < 8; ++nt) {
            float2 wv = *(const float2*)(Wfc + 2 * (nt * 16 + m16));
            w0[nt] = wv.x;
            w1[nt] = wv.y;
        }
        float b0 = bfc[0], b1 = bfc[1];
#pragma unroll
        for (int r = 0; r < 4; ++r) {
            float p0 = 0.f, p1 = 0.f;
#pragma unroll
            for (int nt = 0; nt < 8; ++nt) {
                float v = fmaxf(acc[nt][r] + bcol[nt], 0.f);   // relu (layer2)
                p0 += v * w0[nt];
                p1 += v * w1[nt];
            }
#pragma unroll
            for (int off = 1; off < 16; off <<= 1) {
                p0 += __shfl_xor(p0, off, 64);
                p1 += __shfl_xor(p1, off, 64);
            }
            int row = row_base + quad * 4 + r;
            if (m16 == 0 && row < n) {
                float2 o;
                o.x = p0 + b0;
                o.y = p1 + b1;
                *(float2*)(fcout + 2 * (size_t)row) = o;
            }
        }
    } else {
#pragma unroll
        for (int r = 0; r < 4; ++r) {
            int row = row_base + quad * 4 + r;
            if (row >= n) continue;
            unsigned short* opb = outb + ((size_t)row << 7) + m16;
#pragma unroll
            for (int nt = 0; nt < 8; ++nt) {
                float v = acc[nt][r] + bcol[nt];
                if (relu) v = fmaxf(v, 0.f);
                opb[nt * 16] = f16_bits(v);
            }
        }
    }
}

extern "C" void kernel_launch(void* const* d_in, const int* in_sizes, int n_in,
                              void* d_out, int out_size, void* d_ws, size_t ws_size,
                              hipStream_t stream) {
    const float* x   = (const float*)d_in[0];
    const int* edge  = (const int*)d_in[1];
    const float* W1l = (const float*)d_in[2];
    const float* W1r = (const float*)d_in[3];
    const float* b1  = (const float*)d_in[4];
    const float* W2l = (const float*)d_in[5];
    const float* W2r = (const float*)d_in[6];
    const float* b2  = (const float*)d_in[7];
    const float* Wfc = (const float*)d_in[8];
    const float* bfc = (const float*)d_in[9];
    float* out = (float*)d_out;

    const int n = NN;
    const int* src = edge;        // edge_index[0]
    const int* dst = edge + NE;   // edge_index[1]

    char* ws = (char*)d_ws;
    size_t off = 0;
    auto alloc = [&](size_t bytes) -> char* {
        char* p = ws + off;
        off = (off + bytes + 511) & ~(size_t)511;
        return p;
    };
    int* deg4             = (int*)alloc((size_t)NN * NCHK * 4);
    short* wf             = (short*)alloc((size_t)4 * 16384 * 2);
    unsigned short* col   = (unsigned short*)alloc((size_t)NN * CSTRIDE * 2);
    unsigned short* xb    = (unsigned short*)alloc((size_t)(NN + 1) * 128 * 2);
    unsigned short* aggb  = (unsigned short*)alloc((size_t)NN * 128 * 2);
    unsigned short* h1b   = (unsigned short*)alloc((size_t)(NN + 1) * 128 * 2);
    (void)ws_size; (void)in_sizes; (void)n_in; (void)out_size;

    hipMemsetAsync(deg4, 0, (size_t)NN * NCHK * 4, stream);
    k1_kernel<<<K1_GRID, 256, 0, stream>>>(x, xb, W1l, W1r, W2l, W2r, wf,
                                           deg4, col, src, dst, h1b);

    agg_kernel<<<(n + 3) / 4, 256, 0, stream>>>(xb, col, deg4, aggb, n);
    gemm_mfma<<<(n + 63) / 64, 256, 0, stream>>>(aggb, xb, wf, wf + 16384, b1, h1b,
                                                 (const float*)0, (const float*)0, (float*)0, n, 1);
    agg_kernel<<<(n + 3) / 4, 256, 0, stream>>>(h1b, col, deg4, aggb, n);
    gemm_mfma<<<(n + 63) / 64, 256, 0, stream>>>(aggb, h1b, wf + 2 * 16384, wf + 3 * 16384, b2,
                                                 (unsigned short*)0, Wfc, bfc, out, n, 1);
}

// Round 13
// 216.565 us; speedup vs baseline: 1.1720x; 1.1085x over previous
//
#include <hip/hip_runtime.h>

#define NN 50000
#define NE 800000
#define DEGCAP 64                              // max in-degree (Poisson(16): P(>64)~1e-15)

// XCD-partitioned scatter geometry (r8-validated)
#define NXCD 8
#define NPS ((NN + NXCD - 1) / NXCD)           // 6250 nodes per XCD slot
#define SEPB 4096                              // edges per chunk
#define NCHUNK ((NE + SEPB - 1) / SEPB)        // 196
#define SCAT_GRID (NCHUNK * NXCD)              // 1568

// setup kernel block partition
#define CVT_BLKS 6250                          // NN*128/4/256 exactly
#define PREP_BLKS 32
#define ZERO_BLKS 50                           // 49 for deg (12500 int4), 1 for zero-rows
#define SETUP_GRID (CVT_BLKS + PREP_BLKS + ZERO_BLKS)

typedef short short8 __attribute__((ext_vector_type(8)));
typedef short short4v __attribute__((ext_vector_type(4)));
typedef float f32x4 __attribute__((ext_vector_type(4)));
typedef _Float16 half8v __attribute__((ext_vector_type(8)));

__device__ inline unsigned short f16_bits(float f) {
    _Float16 h = (_Float16)f;                  // v_cvt_f16_f32, RNE
    return __builtin_bit_cast(unsigned short, h);
}

// ---- fused setup: cvt x->fp16 | weight prep | zero deg + zero-rows ---------
__global__ __launch_bounds__(256) void setup_kernel(const float* __restrict__ x,
                                                    unsigned short* __restrict__ xb,
                                                    const float* __restrict__ W0,
                                                    const float* __restrict__ W1,
                                                    const float* __restrict__ W2,
                                                    const float* __restrict__ W3,
                                                    short* __restrict__ wf,
                                                    int* __restrict__ deg,
                                                    unsigned short* __restrict__ h1b) {
    int b = blockIdx.x;
    if (b < CVT_BLKS) {                       // x -> fp16 (one float4/thread, exact)
        int i = b * 256 + threadIdx.x;
        float4 v = ((const float4*)x)[i];
        short4v r;
        r[0] = (short)f16_bits(v.x);
        r[1] = (short)f16_bits(v.y);
        r[2] = (short)f16_bits(v.z);
        r[3] = (short)f16_bits(v.w);
        ((short4v*)xb)[i] = r;
    } else if (b < CVT_BLKS + PREP_BLKS) {    // weight fragment reorder, single fp16
        int t = (b - CVT_BLKS) * 256 + threadIdx.x;   // 0..8191
        int mat = t >> 11;
        const float* W = (mat == 0) ? W0 : (mat == 1) ? W1 : (mat == 2) ? W2 : W3;
        short* out = wf + (size_t)mat * 16384;
        int r = t & 2047;
        int nt = r >> 8;
        int kc = (r >> 6) & 3;
        int lane = r & 63;
        int n = nt * 16 + (lane & 15);
        int kbase = kc * 32 + ((lane >> 4) << 3);
        short8 vh;
#pragma unroll
        for (int j = 0; j < 8; ++j) {
            float w = W[(size_t)(kbase + j) * 128 + n];
            vh[j] = (short)f16_bits(w);
        }
        size_t o = ((size_t)((nt * 4 + kc) * 64 + lane)) * 8;
        *(short8*)(out + o) = vh;
    } else {                                  // zero deg counters + zero feature rows
        int bl = b - CVT_BLKS - PREP_BLKS;
        int idx = bl * 256 + threadIdx.x;
        if (idx < (NN / 4)) ((int4*)deg)[idx] = make_int4(0, 0, 0, 0);
        if (bl == ZERO_BLKS - 1) {            // this block's threads are all past 12500
            int t = threadIdx.x;
            short8 z = {0, 0, 0, 0, 0, 0, 0, 0};
            if (t < 16) *(short8*)(xb + ((size_t)NN << 7) + (t << 3)) = z;
            else if (t < 32) *(short8*)(h1b + ((size_t)NN << 7) + ((t - 16) << 3)) = z;
        }
    }
}

// ---- edge scatter, XCD-partitioned dst ranges + u16 payload (r8 champion) --
// blockIdx&7 = stable XCD class; slot k commits only dst in its 6250-node
// range -> every deg/col line owned by ONE XCD's L2 (one writeback). col
// stores are nt (write-only stream, don't allocate in L2).
__global__ __launch_bounds__(256) void scatter_kernel(const int* __restrict__ src,
                                                      const int* __restrict__ dst,
                                                      int* __restrict__ deg,
                                                      unsigned short* __restrict__ col, int ne) {
    int slot8 = blockIdx.x & 7;
    int chunk = blockIdx.x >> 3;
    int lo = slot8 * NPS, hi = lo + NPS;
    int base = chunk * SEPB;
    int end = base + SEPB;
    if (end > ne) end = ne;
    for (int i = base + threadIdx.x; i < end; i += 256) {
        int d = dst[i];
        if (d >= lo && d < hi) {
            int s = src[i];
            int sl = atomicAdd(&deg[d], 1);
            __builtin_nontemporal_store((unsigned short)s, col + ((size_t)d << 6) + sl);
        }
    }
}

// ---------------- mean aggregation: fp16 in, fp32 acc, fp16 out --------------
// r8 champion structure: one wave per node (50k waves), 4 edge-slots x 16
// feature-lanes, coalesced 256B row reads, 16 edges in flight. col loads and
// output stores are nt (streams) so the 12.8MB gather table keeps L2.
__global__ __launch_bounds__(256) void agg_kernel(const unsigned short* __restrict__ hb,
                                                  const unsigned short* __restrict__ col,
                                                  const int* __restrict__ deg,
                                                  unsigned short* __restrict__ outb, int n) {
    int node = blockIdx.x * 4 + (threadIdx.x >> 6);
    if (node >= n) return;
    int lane = threadIdx.x & 63;
    int slot = lane >> 4, sub = lane & 15;
    int dg = deg[node];
    const unsigned short* base = hb + (sub << 3);
    const unsigned short* cp = col + ((size_t)node << 6);
    float acc[8];
#pragma unroll
    for (int j = 0; j < 8; ++j) acc[j] = 0.f;

    for (int e0 = slot; e0 < dg; e0 += 16) {
        int c[4];
#pragma unroll
        for (int j = 0; j < 4; ++j) {
            int e = e0 + 4 * j;
            int cc = __builtin_nontemporal_load(cp + (e < DEGCAP ? e : 0));
            c[j] = (e < dg) ? cc : NN;                 // junk/overflow lanes -> zero row
        }
        half8v v[4];
#pragma unroll
        for (int j = 0; j < 4; ++j) v[j] = *(const half8v*)(base + ((size_t)c[j] << 7));
        half8v s = (v[0] + v[1]) + (v[2] + v[3]);      // fp16 tree (r5/r6-validated)
#pragma unroll
        for (int q = 0; q < 8; ++q) acc[q] += (float)s[q];
    }
#pragma unroll
    for (int j = 0; j < 8; ++j) {
        acc[j] += __shfl_xor(acc[j], 16, 64);
        acc[j] += __shfl_xor(acc[j], 32, 64);
    }
    if (slot == 0) {
        float s = 1.0f / (float)(dg > 0 ? dg : 1);
        short8 o;
#pragma unroll
        for (int j = 0; j < 8; ++j) o[j] = (short)f16_bits(acc[j] * s);
        __builtin_nontemporal_store(o, (short8*)(outb + ((size_t)node << 7) + (sub << 3)));
    }
}

// ---------------- fused dual GEMM, fp16 MFMA (+opt. fused FC) ----------------
__global__ __launch_bounds__(256) void gemm_mfma(const unsigned short* __restrict__ A0b,
                                                 const unsigned short* __restrict__ A1b,
                                                 const short* __restrict__ Wf0,
                                                 const short* __restrict__ Wf1,
                                                 const float* __restrict__ bias,
                                                 unsigned short* __restrict__ outb,
                                                 const float* __restrict__ Wfc,
                                                 const float* __restrict__ bfc,
                                                 float* __restrict__ fcout,
                                                 int n, int relu) {
    int lane = threadIdx.x & 63;
    int wave = threadIdx.x >> 6;
    int quad = lane >> 4, m16 = lane & 15;
    int row_base = blockIdx.x * 64 + wave * 16;
    int arow = row_base + m16;
    if (arow > n - 1) arow = n - 1;            // clamp (padding rows never stored)

    // hoist A fragments (8 loads) out of the K loop
    const unsigned short* ap0 = A0b + ((size_t)arow << 7) + (quad << 3);
    const unsigned short* ap1 = A1b + ((size_t)arow << 7) + (quad << 3);
    half8v a0[4], a1[4];
#pragma unroll
    for (int kc = 0; kc < 4; ++kc) {
        a0[kc] = *(const half8v*)(ap0 + kc * 32);
        a1[kc] = *(const half8v*)(ap1 + kc * 32);
    }

    f32x4 acc[8];
#pragma unroll
    for (int nt = 0; nt < 8; ++nt) acc[nt] = (f32x4){0.f, 0.f, 0.f, 0.f};

#pragma unroll
    for (int kc = 0; kc < 4; ++kc) {
        const short* wp0 = Wf0 + ((size_t)kc * 64 + lane) * 8;
        const short* wp1 = Wf1 + ((size_t)kc * 64 + lane) * 8;
#pragma unroll
        for (int nt = 0; nt < 8; ++nt) {
            half8v b0 = *(const half8v*)(wp0 + (size_t)nt * 2048);
            half8v b1 = *(const half8v*)(wp1 + (size_t)nt * 2048);
            acc[nt] = __builtin_amdgcn_mfma_f32_16x16x32_f16(a0[kc], b0, acc[nt], 0, 0, 0);
            acc[nt] = __builtin_amdgcn_mfma_f32_16x16x32_f16(a1[kc], b1, acc[nt], 0, 0, 0);
        }
    }

    // epilogue: C/D layout col = lane&15, row = quad*4 + reg
    float bcol[8];
#pragma unroll
    for (int nt = 0; nt < 8; ++nt) bcol[nt] = bias[nt * 16 + m16];

    if (Wfc) {
        // fused final FC: lane holds cols nt*16+m16; reduce over 16 m16-lanes
        float w0[8], w1[8];
#pragma unroll
        for (int nt = 0; nt < 8; ++nt) {
            float2 wv = *(const float2*)(Wfc + 2 * (nt * 16 + m16));
            w0[nt] = wv.x;
            w1[nt] = wv.y;
        }
        float b0 = bfc[0], b1 = bfc[1];
#pragma unroll
        for (int r = 0; r < 4; ++r) {
            float p0 = 0.f, p1 = 0.f;
#pragma unroll
            for (int nt = 0; nt < 8; ++nt) {
                float v = fmaxf(acc[nt][r] + bcol[nt], 0.f);   // relu (layer2)
                p0 += v * w0[nt];
                p1 += v * w1[nt];
            }
#pragma unroll
            for (int off = 1; off < 16; off <<= 1) {
                p0 += __shfl_xor(p0, off, 64);
                p1 += __shfl_xor(p1, off, 64);
            }
            int row = row_base + quad * 4 + r;
            if (m16 == 0 && row < n) {
                float2 o;
                o.x = p0 + b0;
                o.y = p1 + b1;
                *(float2*)(fcout + 2 * (size_t)row) = o;
            }
        }
    } else {
#pragma unroll
        for (int r = 0; r < 4; ++r) {
            int row = row_base + quad * 4 + r;
            if (row >= n) continue;
            unsigned short* opb = outb + ((size_t)row << 7) + m16;
#pragma unroll
            for (int nt = 0; nt < 8; ++nt) {
                float v = acc[nt][r] + bcol[nt];
                if (relu) v = fmaxf(v, 0.f);
                opb[nt * 16] = f16_bits(v);
            }
        }
    }
}

extern "C" void kernel_launch(void* const* d_in, const int* in_sizes, int n_in,
                              void* d_out, int out_size, void* d_ws, size_t ws_size,
                              hipStream_t stream) {
    const float* x   = (const float*)d_in[0];
    const int* edge  = (const int*)d_in[1];
    const float* W1l = (const float*)d_in[2];
    const float* W1r = (const float*)d_in[3];
    const float* b1  = (const float*)d_in[4];
    const float* W2l = (const float*)d_in[5];
    const float* W2r = (const float*)d_in[6];
    const float* b2  = (const float*)d_in[7];
    const float* Wfc = (const float*)d_in[8];
    const float* bfc = (const float*)d_in[9];
    float* out = (float*)d_out;

    const int n = NN, ne = NE;
    const int* src = edge;        // edge_index[0]
    const int* dst = edge + ne;   // edge_index[1]

    char* ws = (char*)d_ws;
    size_t off = 0;
    auto alloc = [&](size_t bytes) -> char* {
        char* p = ws + off;
        off = (off + bytes + 511) & ~(size_t)511;
        return p;
    };
    int* deg              = (int*)alloc((size_t)NN * 4);
    short* wf             = (short*)alloc((size_t)4 * 16384 * 2);
    unsigned short* col   = (unsigned short*)alloc((size_t)NN * DEGCAP * 2);
    unsigned short* xb    = (unsigned short*)alloc((size_t)(n + 1) * 128 * 2);
    unsigned short* aggb  = (unsigned short*)alloc((size_t)n * 128 * 2);
    unsigned short* h1b   = (unsigned short*)alloc((size_t)(n + 1) * 128 * 2);
    (void)ws_size; (void)in_sizes; (void)n_in; (void)out_size;

    setup_kernel<<<SETUP_GRID, 256, 0, stream>>>(x, xb, W1l, W1r, W2l, W2r, wf, deg, h1b);
    scatter_kernel<<<SCAT_GRID, 256, 0, stream>>>(src, dst, deg, col, ne);

    agg_kernel<<<(n + 3) / 4, 256, 0, stream>>>(xb, col, deg, aggb, n);
    gemm_mfma<<<(n + 63) / 64, 256, 0, stream>>>(aggb, xb, wf, wf + 16384, b1, h1b,
                                                 (const float*)0, (const float*)0, (float*)0, n, 1);
    agg_kernel<<<(n + 3) / 4, 256, 0, stream>>>(h1b, col, deg, aggb, n);
    gemm_mfma<<<(n + 63) / 64, 256, 0, stream>>>(aggb, h1b, wf + 2 * 16384, wf + 3 * 16384, b2,
                                                 (unsigned short*)0, Wfc, bfc, out, n, 1);
}